// Round 1
// baseline (219.544 us; speedup 1.0000x reference)
//
#include <hip/hip_runtime.h>

// MHA forward, full-bf16 MFMA pipeline.
// ws layout (bytes): xb[8MB] | Wt[6MB: [3][1024][1024] bf16 N-major] | Wot[2MB]
//                    | qkv[24MB: [3][B][H][T][64]] | Y[8MB: [B][T][1024]]
// Total 48MB of d_ws.

typedef short v8s __attribute__((ext_vector_type(8)));
typedef float v4f __attribute__((ext_vector_type(4)));

#define DEVI __device__ __forceinline__

#define B_SZ 2
#define T_SEQ 2048
#define NH 16
#define HS 64
#define CEMB 1024
#define MROWS (B_SZ * T_SEQ)   // 4096

DEVI unsigned short f2bf(float f) {
  union { float f; unsigned u; } c; c.f = f;
  unsigned u = c.u;
  unsigned r = (u + 0x7FFFu + ((u >> 16) & 1u)) >> 16;   // RNE
  return (unsigned short)r;
}

// ---------------- x -> bf16 ----------------
__global__ void cvt_f32_bf16x4(const float* __restrict__ in,
                               unsigned short* __restrict__ out, int n4) {
  int i = blockIdx.x * blockDim.x + threadIdx.x;
  if (i >= n4) return;
  float4 v = ((const float4*)in)[i];
  ushort4 o;
  o.x = f2bf(v.x); o.y = f2bf(v.y); o.z = f2bf(v.z); o.w = f2bf(v.w);
  ((ushort4*)out)[i] = o;
}

// ------------- transpose f32[R][C] -> bf16[C][R], per z-slice -------------
__global__ void transpose_cvt(const float* __restrict__ in,
                              unsigned short* __restrict__ out, int R, int C) {
  __shared__ float tile[32][33];
  size_t zoff = (size_t)blockIdx.z * R * C;
  in += zoff; out += zoff;
  int c0 = blockIdx.x * 32, r0 = blockIdx.y * 32;
  int tx = threadIdx.x, ty = threadIdx.y;
#pragma unroll
  for (int j = 0; j < 4; ++j) {
    int r = r0 + ty + j * 8;
    tile[ty + j * 8][tx] = in[(size_t)r * C + c0 + tx];
  }
  __syncthreads();
#pragma unroll
  for (int j = 0; j < 4; ++j) {
    int c = c0 + ty + j * 8;
    out[(size_t)c * R + r0 + tx] = f2bf(tile[tx][ty + j * 8]);
  }
}

// ------------- GEMM: C = A[M][K] x Bt[N][K]^T, bf16 in, f32 acc -------------
// 128x128 tile, BK=32, 256 threads = 4 waves (2x2), 16x16x32 MFMA.
// MODE 0: QKV epilogue -> bf16 scatter to [p][B][H][T][64], Q scaled by 0.125
// MODE 1: out-proj epilogue -> f32 [M][1024] + bias
template <int MODE>
__global__ __launch_bounds__(256, 2) void gemm_bt(
    const unsigned short* __restrict__ A, const unsigned short* __restrict__ Bt,
    void* __restrict__ Cout, const float* __restrict__ bias, int Ksz) {
  __shared__ __align__(16) unsigned short As[128][40];
  __shared__ __align__(16) unsigned short Bs[128][40];

  const int tid = threadIdx.x;
  const int lane = tid & 63, w = tid >> 6;
  const int wm = w >> 1, wn = w & 1;
  const int lr = lane & 15, lg = lane >> 4;
  const int mb = blockIdx.y * 128, nb = blockIdx.x * 128;

  v4f acc[4][4];
  v4f zero = {0.f, 0.f, 0.f, 0.f};
#pragma unroll
  for (int i = 0; i < 4; ++i)
#pragma unroll
    for (int j = 0; j < 4; ++j) acc[i][j] = zero;

  const int arow = tid >> 1, acol = (tid & 1) << 4;

  for (int kb = 0; kb < Ksz; kb += 32) {
    __syncthreads();
    {
      const int4* sa = (const int4*)(A + (size_t)(mb + arow) * Ksz + kb + acol);
      int4 a0 = sa[0], a1 = sa[1];
      const int4* sb = (const int4*)(Bt + (size_t)(nb + arow) * Ksz + kb + acol);
      int4 b0 = sb[0], b1 = sb[1];
      *(int4*)&As[arow][acol] = a0;
      *(int4*)&As[arow][acol + 8] = a1;
      *(int4*)&Bs[arow][acol] = b0;
      *(int4*)&Bs[arow][acol + 8] = b1;
    }
    __syncthreads();
    v8s af[4], bfr[4];
#pragma unroll
    for (int i = 0; i < 4; ++i) {
      af[i] = *(const v8s*)&As[wm * 64 + i * 16 + lr][lg * 8];
      bfr[i] = *(const v8s*)&Bs[wn * 64 + i * 16 + lr][lg * 8];
    }
#pragma unroll
    for (int i = 0; i < 4; ++i)
#pragma unroll
      for (int j = 0; j < 4; ++j)
        acc[i][j] = __builtin_amdgcn_mfma_f32_16x16x32_bf16(af[i], bfr[j], acc[i][j], 0, 0, 0);
  }

#pragma unroll
  for (int i = 0; i < 4; ++i) {
    int mrow0 = mb + wm * 64 + i * 16 + lg * 4;
#pragma unroll
    for (int j = 0; j < 4; ++j) {
      int ncol = nb + wn * 64 + j * 16 + lr;
      if (MODE == 0) {
        int p = ncol >> 10, rem = ncol & 1023, h = rem >> 6, d = rem & 63;
        float sc = (p == 0) ? 0.125f : 1.0f;  // fold 1/sqrt(64) into Q
        unsigned short* out = (unsigned short*)Cout;
#pragma unroll
        for (int r = 0; r < 4; ++r) {
          int mrow = mrow0 + r;
          int b = mrow >> 11, t = mrow & 2047;
          out[((size_t)((p * B_SZ + b) * NH + h) * T_SEQ + t) * HS + d] =
              f2bf(acc[i][j][r] * sc);
        }
      } else {
        float* out = (float*)Cout;
        float bv = bias[ncol];
#pragma unroll
        for (int r = 0; r < 4; ++r)
          out[(size_t)(mrow0 + r) * CEMB + ncol] = acc[i][j][r] + bv;
      }
    }
  }
}

// ------------- causal flash attention -------------
// grid (T/64, B*H), 256 threads = 4 waves; wave w owns q-rows qb*64+w*16..+15.
// K tile [64][64] and Vt tile [64(d)][64(s)] in LDS, XOR-swizzled
// (byte ^= (row&7)<<4) to kill the 128B-stride bank conflict on ds_read_b128.
__global__ __launch_bounds__(256, 2) void attn_kernel(
    const unsigned short* __restrict__ Qg, const unsigned short* __restrict__ Kg,
    const unsigned short* __restrict__ Vg, unsigned short* __restrict__ Yg) {
  __shared__ __align__(16) unsigned char lds[24 * 1024];
  unsigned char* KsB = lds;             // 8KB
  unsigned char* VtB = lds + 8192;      // 8KB
  unsigned char* PsB = lds + 16384;     // 8KB (4 waves x 2KB)

  const int tid = threadIdx.x;
  const int lane = tid & 63, w = tid >> 6;
  const int lr = lane & 15, lg = lane >> 4;
  const int qb = blockIdx.x, bh = blockIdx.y;

  const unsigned short* Qbase = Qg + (size_t)bh * T_SEQ * HS;
  const unsigned short* Kbase = Kg + (size_t)bh * T_SEQ * HS;
  const unsigned short* Vbase = Vg + (size_t)bh * T_SEQ * HS;

  // Q fragments, hoisted (Q already scaled by 0.125 in QKV epilogue)
  v8s qA[2];
  {
    const unsigned short* qrow = Qbase + (size_t)(qb * 64 + w * 16 + lr) * HS;
    qA[0] = *(const v8s*)(qrow + lg * 8);
    qA[1] = *(const v8s*)(qrow + 32 + lg * 8);
  }

  v4f O[4];
  v4f zero = {0.f, 0.f, 0.f, 0.f};
#pragma unroll
  for (int d = 0; d < 4; ++d) O[d] = zero;
  float l[4] = {0.f, 0.f, 0.f, 0.f};
  float mprev[4] = {-1e30f, -1e30f, -1e30f, -1e30f};

  unsigned char* PsW = PsB + w * 2048;

  for (int sblk = 0; sblk <= qb; ++sblk) {
    __syncthreads();  // prior iteration's K/V reads done
    {  // stage K [64 s][64 d], swizzled
      int r = tid >> 2, cb = (tid & 3) << 4;
      const int4* src = (const int4*)(Kbase + (size_t)(sblk * 64 + r) * HS + cb);
      int4 v0 = src[0], v1 = src[1];
      int c16 = cb >> 3;
      *(int4*)(KsB + r * 128 + (((c16) ^ (r & 7)) << 4)) = v0;
      *(int4*)(KsB + r * 128 + (((c16 + 1) ^ (r & 7)) << 4)) = v1;
    }
    {  // stage V transposed -> Vt[d][s], swizzled
      int s = tid >> 2, db = (tid & 3) << 4;
      const int4* src = (const int4*)(Vbase + (size_t)(sblk * 64 + s) * HS + db);
      int4 v0 = src[0], v1 = src[1];
      const unsigned short* e0 = (const unsigned short*)&v0;
      const unsigned short* e1 = (const unsigned short*)&v1;
      int sc = s >> 3, so = (s & 7) << 1;
#pragma unroll
      for (int j = 0; j < 8; ++j) {
        int d0 = db + j;
        *(unsigned short*)(VtB + d0 * 128 + ((sc ^ (d0 & 7)) << 4) + so) = e0[j];
        int d1 = db + 8 + j;
        *(unsigned short*)(VtB + d1 * 128 + ((sc ^ (d1 & 7)) << 4) + so) = e1[j];
      }
    }
    __syncthreads();

    // S = Q K^T (scaled), C-layout: row = lg*4+r, col = cf*16+lr
    v4f S[4];
#pragma unroll
    for (int cf = 0; cf < 4; ++cf) {
      S[cf] = zero;
#pragma unroll
      for (int ks = 0; ks < 2; ++ks) {
        int srow = cf * 16 + lr, c16 = ks * 4 + lg;
        v8s kb = *(const v8s*)(KsB + srow * 128 + ((c16 ^ (srow & 7)) << 4));
        S[cf] = __builtin_amdgcn_mfma_f32_16x16x32_bf16(qA[ks], kb, S[cf], 0, 0, 0);
      }
    }

    if (sblk == qb) {  // causal mask on diagonal block
#pragma unroll
      for (int cf = 0; cf < 4; ++cf)
#pragma unroll
        for (int r = 0; r < 4; ++r)
          if (cf * 16 + lr > w * 16 + lg * 4 + r) S[cf][r] = -1e30f;
    }

    // online softmax (row lives in 16 lanes: shfl_xor 1,2,4,8)
#pragma unroll
    for (int r = 0; r < 4; ++r) {
      float mx = fmaxf(fmaxf(S[0][r], S[1][r]), fmaxf(S[2][r], S[3][r]));
      mx = fmaxf(mx, __shfl_xor(mx, 1));
      mx = fmaxf(mx, __shfl_xor(mx, 2));
      mx = fmaxf(mx, __shfl_xor(mx, 4));
      mx = fmaxf(mx, __shfl_xor(mx, 8));
      float mn = fmaxf(mprev[r], mx);
      float alpha = __expf(mprev[r] - mn);
      mprev[r] = mn;
      float sum = 0.f;
#pragma unroll
      for (int cf = 0; cf < 4; ++cf) {
        float p = __expf(S[cf][r] - mn);
        S[cf][r] = p;
        sum += p;
      }
      sum += __shfl_xor(sum, 1);
      sum += __shfl_xor(sum, 2);
      sum += __shfl_xor(sum, 4);
      sum += __shfl_xor(sum, 8);
      l[r] = l[r] * alpha + sum;
      O[0][r] *= alpha; O[1][r] *= alpha; O[2][r] *= alpha; O[3][r] *= alpha;
    }

    // P -> bf16 -> per-wave swizzled LDS (A-frag layout round trip)
#pragma unroll
    for (int cf = 0; cf < 4; ++cf) {
      int col = cf * 16 + lr;
      int cc = col >> 3, co = (col & 7) << 1;
#pragma unroll
      for (int r = 0; r < 4; ++r) {
        int row = lg * 4 + r;
        *(unsigned short*)(PsW + row * 128 + ((cc ^ (row & 7)) << 4) + co) =
            f2bf(S[cf][r]);
      }
    }

    v8s pA[2];
#pragma unroll
    for (int ks = 0; ks < 2; ++ks) {
      int c16 = ks * 4 + lg;
      pA[ks] = *(const v8s*)(PsW + lr * 128 + ((c16 ^ (lr & 7)) << 4));
    }
#pragma unroll
    for (int df = 0; df < 4; ++df) {
#pragma unroll
      for (int ks = 0; ks < 2; ++ks) {
        int drow = df * 16 + lr, c16 = ks * 4 + lg;
        v8s vb = *(const v8s*)(VtB + drow * 128 + ((c16 ^ (drow & 7)) << 4));
        O[df] = __builtin_amdgcn_mfma_f32_16x16x32_bf16(pA[ks], vb, O[df], 0, 0, 0);
      }
    }
  }

  // epilogue: Y[b][t][h*64+d] bf16, concat-head layout
  int trow = qb * 64 + w * 16 + lg * 4;
  int b = bh >> 4, h = bh & 15;
#pragma unroll
  for (int df = 0; df < 4; ++df) {
    int col = h * 64 + df * 16 + lr;
#pragma unroll
    for (int r = 0; r < 4; ++r) {
      float o = O[df][r] / l[r];
      Yg[((size_t)b * T_SEQ + trow + r) * (NH * HS) + col] = f2bf(o);
    }
  }
}

extern "C" void kernel_launch(void* const* d_in, const int* in_sizes, int n_in,
                              void* d_out, int out_size, void* d_ws, size_t ws_size,
                              hipStream_t stream) {
  (void)in_sizes; (void)n_in; (void)out_size; (void)ws_size;
  const float* x  = (const float*)d_in[0];
  const float* Wq = (const float*)d_in[1];
  const float* Wk = (const float*)d_in[2];
  const float* Wv = (const float*)d_in[3];
  const float* Wo = (const float*)d_in[4];
  const float* bo = (const float*)d_in[5];

  unsigned char* ws = (unsigned char*)d_ws;
  unsigned short* xb  = (unsigned short*)(ws);                      // 8MB
  unsigned short* Wt  = (unsigned short*)(ws + (8u << 20));         // 6MB
  unsigned short* Wot = (unsigned short*)(ws + (14u << 20));        // 2MB
  unsigned short* qkv = (unsigned short*)(ws + (16u << 20));        // 24MB
  unsigned short* Y   = (unsigned short*)(ws + (40u << 20));        // 8MB

  // 1. x -> bf16
  cvt_f32_bf16x4<<<4096, 256, 0, stream>>>(x, xb, (MROWS * CEMB) / 4);

  // 2. weights -> bf16, transposed to [N][K]
  dim3 tb(32, 8);
  transpose_cvt<<<dim3(2, 32, 16), tb, 0, stream>>>(Wq, Wt, 1024, 64);
  transpose_cvt<<<dim3(2, 32, 16), tb, 0, stream>>>(Wk, Wt + (1u << 20), 1024, 64);
  transpose_cvt<<<dim3(2, 32, 16), tb, 0, stream>>>(Wv, Wt + (2u << 20), 1024, 64);
  transpose_cvt<<<dim3(32, 32, 1), tb, 0, stream>>>(Wo, Wot, 1024, 1024);

  // 3. fused QKV projection: [4096][1024] x [3072][1024]^T
  gemm_bt<0><<<dim3(24, 32), 256, 0, stream>>>(xb, Wt, qkv, nullptr, 1024);

  // 4. causal flash attention
  const unsigned short* Qp = qkv;
  const unsigned short* Kp = qkv + (size_t)B_SZ * NH * T_SEQ * HS;
  const unsigned short* Vp = qkv + (size_t)2 * B_SZ * NH * T_SEQ * HS;
  attn_kernel<<<dim3(T_SEQ / 64, B_SZ * NH), 256, 0, stream>>>(Qp, Kp, Vp, Y);

  // 5. output projection + bias -> f32 d_out
  gemm_bt<1><<<dim3(8, 32), 256, 0, stream>>>(Y, Wot, d_out, bo, 1024);
}

// Round 2
// 171.892 us; speedup vs baseline: 1.2772x; 1.2772x over previous
//
#include <hip/hip_runtime.h>

// MHA forward, full-bf16 MFMA pipeline.
// ws layout (bytes): xb[8MB] | Wt[6MB: [3][1024][1024] bf16 N-major] | Wot[2MB]
//                    | qkv[24MB: Q,K:[B][H][T][64], V:[B][H][64][T]] | Y[8MB]

typedef short v8s __attribute__((ext_vector_type(8)));
typedef float v4f __attribute__((ext_vector_type(4)));

#define DEVI __device__ __forceinline__

#define B_SZ 2
#define T_SEQ 2048
#define NH 16
#define HS 64
#define CEMB 1024
#define MROWS (B_SZ * T_SEQ)   // 4096

DEVI unsigned short f2bf(float f) {
  union { float f; unsigned u; } c; c.f = f;
  unsigned u = c.u;
  unsigned r = (u + 0x7FFFu + ((u >> 16) & 1u)) >> 16;   // RNE
  return (unsigned short)r;
}

// ---------------- x -> bf16 ----------------
__global__ void cvt_f32_bf16x4(const float* __restrict__ in,
                               unsigned short* __restrict__ out, int n4) {
  int i = blockIdx.x * blockDim.x + threadIdx.x;
  if (i >= n4) return;
  float4 v = ((const float4*)in)[i];
  ushort4 o;
  o.x = f2bf(v.x); o.y = f2bf(v.y); o.z = f2bf(v.z); o.w = f2bf(v.w);
  ((ushort4*)out)[i] = o;
}

// ------------- transpose f32[R][C] -> bf16[C][R], per z-slice -------------
__global__ void transpose_cvt(const float* __restrict__ in,
                              unsigned short* __restrict__ out, int R, int C) {
  __shared__ float tile[32][33];
  size_t zoff = (size_t)blockIdx.z * R * C;
  in += zoff; out += zoff;
  int c0 = blockIdx.x * 32, r0 = blockIdx.y * 32;
  int tx = threadIdx.x, ty = threadIdx.y;
#pragma unroll
  for (int j = 0; j < 4; ++j) {
    int r = r0 + ty + j * 8;
    tile[ty + j * 8][tx] = in[(size_t)r * C + c0 + tx];
  }
  __syncthreads();
#pragma unroll
  for (int j = 0; j < 4; ++j) {
    int c = c0 + ty + j * 8;
    out[(size_t)c * R + r0 + tx] = f2bf(tile[tx][ty + j * 8]);
  }
}

// ------------- GEMM: C = A[M][K] x Bt[N][K]^T, bf16 in, f32 acc -------------
// MODE 0: QKV epilogue -> bf16 scatter; Q scaled 0.125; V written TRANSPOSED
//         (Q,K: [b][h][t][d], V: [b][h][d][t])
// MODE 1: out-proj epilogue -> f32 [M][1024] + bias
template <int MODE>
__global__ __launch_bounds__(256, 2) void gemm_bt(
    const unsigned short* __restrict__ A, const unsigned short* __restrict__ Bt,
    void* __restrict__ Cout, const float* __restrict__ bias, int Ksz) {
  __shared__ __align__(16) unsigned short As[128][40];
  __shared__ __align__(16) unsigned short Bs[128][40];

  const int tid = threadIdx.x;
  const int lane = tid & 63, w = tid >> 6;
  const int wm = w >> 1, wn = w & 1;
  const int lr = lane & 15, lg = lane >> 4;
  const int mb = blockIdx.y * 128, nb = blockIdx.x * 128;

  v4f acc[4][4];
  v4f zero = {0.f, 0.f, 0.f, 0.f};
#pragma unroll
  for (int i = 0; i < 4; ++i)
#pragma unroll
    for (int j = 0; j < 4; ++j) acc[i][j] = zero;

  const int arow = tid >> 1, acol = (tid & 1) << 4;

  for (int kb = 0; kb < Ksz; kb += 32) {
    __syncthreads();
    {
      const int4* sa = (const int4*)(A + (size_t)(mb + arow) * Ksz + kb + acol);
      int4 a0 = sa[0], a1 = sa[1];
      const int4* sb = (const int4*)(Bt + (size_t)(nb + arow) * Ksz + kb + acol);
      int4 b0 = sb[0], b1 = sb[1];
      *(int4*)&As[arow][acol] = a0;
      *(int4*)&As[arow][acol + 8] = a1;
      *(int4*)&Bs[arow][acol] = b0;
      *(int4*)&Bs[arow][acol + 8] = b1;
    }
    __syncthreads();
    v8s af[4], bfr[4];
#pragma unroll
    for (int i = 0; i < 4; ++i) {
      af[i] = *(const v8s*)&As[wm * 64 + i * 16 + lr][lg * 8];
      bfr[i] = *(const v8s*)&Bs[wn * 64 + i * 16 + lr][lg * 8];
    }
#pragma unroll
    for (int i = 0; i < 4; ++i)
#pragma unroll
      for (int j = 0; j < 4; ++j)
        acc[i][j] = __builtin_amdgcn_mfma_f32_16x16x32_bf16(af[i], bfr[j], acc[i][j], 0, 0, 0);
  }

#pragma unroll
  for (int i = 0; i < 4; ++i) {
    int mrow0 = mb + wm * 64 + i * 16 + lg * 4;
#pragma unroll
    for (int j = 0; j < 4; ++j) {
      int ncol = nb + wn * 64 + j * 16 + lr;
      if (MODE == 0) {
        int p = ncol >> 10, rem = ncol & 1023, h = rem >> 6, d = rem & 63;
        float sc = (p == 0) ? 0.125f : 1.0f;  // fold 1/sqrt(64) into Q
        unsigned short* out = (unsigned short*)Cout;
#pragma unroll
        for (int r = 0; r < 4; ++r) {
          int mrow = mrow0 + r;
          int b = mrow >> 11, t = mrow & 2047;
          size_t off;
          if (p < 2)
            off = ((size_t)((p * B_SZ + b) * NH + h) * T_SEQ + t) * HS + d;
          else  // V transposed: [b][h][d][t]
            off = (size_t)(2 * B_SZ * NH) * T_SEQ * HS +
                  ((size_t)(b * NH + h) * HS + d) * T_SEQ + t;
          out[off] = f2bf(acc[i][j][r] * sc);
        }
      } else {
        float* out = (float*)Cout;
        float bv = bias[ncol];
#pragma unroll
        for (int r = 0; r < 4; ++r)
          out[(size_t)(mrow0 + r) * CEMB + ncol] = acc[i][j][r] + bv;
      }
    }
  }
}

// ------------- causal flash attention -------------
// 512 threads = 8 waves; wave w owns q rows qc*128 + w*16 .. +15.
// K tile [128 s][64 d] and Vt tile [64 d][128 s] in LDS, chunk-XOR swizzled:
// addr(row,c16) = row*rowB + ((c16 ^ (row & (nch-1))) << 4).
// Per-wave P[16 q][128 s] in LDS (same swizzle, 16 chunks/row).
// T14 async split: next tile's global loads issued before compute of current.
// Grid: flat 512, LPT order (longest q-chunk first); bh = idx&31 pins each
// head's K/V to one XCD (idx%8 == bh%8).
__global__ __launch_bounds__(512, 4) void attn_kernel(
    const unsigned short* __restrict__ Qg, const unsigned short* __restrict__ Kg,
    const unsigned short* __restrict__ Vtg, unsigned short* __restrict__ Yg) {
  __shared__ __align__(16) unsigned char lds[64 * 1024];
  unsigned char* KsB = lds;             // 16KB
  unsigned char* VtB = lds + 16384;     // 16KB
  unsigned char* PsB = lds + 32768;     // 32KB (8 waves x 4KB)

  const int tid = threadIdx.x;
  const int lane = tid & 63, w = tid >> 6;
  const int lr = lane & 15, lg = lane >> 4;
  const int qc = 15 - (blockIdx.x >> 5);   // LPT: long blocks first
  const int bh = blockIdx.x & 31;

  const unsigned short* Qbase = Qg + (size_t)bh * T_SEQ * HS;
  const unsigned short* Kbase = Kg + (size_t)bh * T_SEQ * HS;
  const unsigned short* Vtbase = Vtg + (size_t)bh * T_SEQ * HS;  // [64 d][2048 t]

  // staging geometry (per-thread constants)
  const int ks_row = tid >> 3, ks_cb = tid & 7;                 // K: 128x8 chunks
  const int kLds0 = ks_row * 128 + ((ks_cb ^ (ks_row & 7)) << 4);
  const int vs_d = tid >> 4, vs_sc = tid & 15;                  // Vt: 64x16 chunks
  const int vLds0 = vs_d * 256 + ((vs_sc ^ (vs_d & 15)) << 4);
  const unsigned short* Kg0 = Kbase + ks_row * HS + ks_cb * 8;          // +t*8192
  const unsigned short* Vg0 = Vtbase + (size_t)vs_d * T_SEQ + vs_sc * 8;  // +t*128

  // Q fragments, hoisted (Q pre-scaled by 0.125)
  v8s qA[2];
  {
    const unsigned short* qrow = Qbase + (size_t)(qc * 128 + w * 16 + lr) * HS;
    qA[0] = *(const v8s*)(qrow + lg * 8);
    qA[1] = *(const v8s*)(qrow + 32 + lg * 8);
  }

  v4f O[4];
  v4f zero = {0.f, 0.f, 0.f, 0.f};
#pragma unroll
  for (int d = 0; d < 4; ++d) O[d] = zero;
  float l[4] = {0.f, 0.f, 0.f, 0.f};
  float m[4] = {-1e30f, -1e30f, -1e30f, -1e30f};

  unsigned char* PsW = PsB + w * 4096;

  // prologue: tile 0 into regs
  int4 gK0 = *(const int4*)(Kg0);
  int4 gK1 = *(const int4*)(Kg0 + 4096);
  int4 gV0 = *(const int4*)(Vg0);
  int4 gV1 = *(const int4*)(Vg0 + 32 * T_SEQ);

  for (int t = 0; t <= qc; ++t) {
    __syncthreads();  // all reads of previous tile done
    *(int4*)(KsB + kLds0) = gK0;
    *(int4*)(KsB + kLds0 + 8192) = gK1;
    *(int4*)(VtB + vLds0) = gV0;
    *(int4*)(VtB + vLds0 + 8192) = gV1;
    __syncthreads();
    if (t < qc) {  // prefetch next tile (hidden under compute below)
      const unsigned short* kp = Kg0 + (t + 1) * (128 * HS);
      gK0 = *(const int4*)kp;
      gK1 = *(const int4*)(kp + 4096);
      const unsigned short* vp = Vg0 + (t + 1) * 128;
      gV0 = *(const int4*)vp;
      gV1 = *(const int4*)(vp + 32 * T_SEQ);
    }

    // S = Q K^T : C row = q = lg*4+r, col = s = cf*16+lr
    v4f S[8];
#pragma unroll
    for (int cf = 0; cf < 8; ++cf) {
      S[cf] = zero;
#pragma unroll
      for (int ks = 0; ks < 2; ++ks) {
        int srow = cf * 16 + lr;
        v8s kb = *(const v8s*)(KsB + srow * 128 +
                               ((((ks << 2) + lg) ^ (lr & 7)) << 4));
        S[cf] = __builtin_amdgcn_mfma_f32_16x16x32_bf16(qA[ks], kb, S[cf], 0, 0, 0);
      }
    }

    if (t == qc) {  // causal mask on diagonal tile
#pragma unroll
      for (int cf = 0; cf < 8; ++cf)
#pragma unroll
        for (int r = 0; r < 4; ++r)
          if (cf * 16 + lr > w * 16 + lg * 4 + r) S[cf][r] = -1e30f;
    }

    // online softmax: row q = 16 lanes (same lg), reduce via xor 1,2,4,8
#pragma unroll
    for (int r = 0; r < 4; ++r) {
      float mx = fmaxf(fmaxf(fmaxf(S[0][r], S[1][r]), fmaxf(S[2][r], S[3][r])),
                       fmaxf(fmaxf(S[4][r], S[5][r]), fmaxf(S[6][r], S[7][r])));
      mx = fmaxf(mx, __shfl_xor(mx, 1));
      mx = fmaxf(mx, __shfl_xor(mx, 2));
      mx = fmaxf(mx, __shfl_xor(mx, 4));
      mx = fmaxf(mx, __shfl_xor(mx, 8));
      float mn = fmaxf(m[r], mx);
      float alpha = __expf(m[r] - mn);
      m[r] = mn;
      float sum = 0.f;
#pragma unroll
      for (int cf = 0; cf < 8; ++cf) {
        float p = __expf(S[cf][r] - mn);
        S[cf][r] = p;
        sum += p;
      }
      sum += __shfl_xor(sum, 1);
      sum += __shfl_xor(sum, 2);
      sum += __shfl_xor(sum, 4);
      sum += __shfl_xor(sum, 8);
      l[r] = l[r] * alpha + sum;
      O[0][r] *= alpha; O[1][r] *= alpha; O[2][r] *= alpha; O[3][r] *= alpha;
    }

    // P -> bf16 -> per-wave swizzled LDS
#pragma unroll
    for (int cf = 0; cf < 8; ++cf) {
      int cb2 = 2 * cf + (lr >> 3), co = (lr & 7) << 1;
#pragma unroll
      for (int r = 0; r < 4; ++r) {
        int row = lg * 4 + r;
        *(unsigned short*)(PsW + row * 256 + ((cb2 ^ row) << 4) + co) =
            f2bf(S[cf][r]);
      }
    }

    v8s pA[4];
#pragma unroll
    for (int k2 = 0; k2 < 4; ++k2)
      pA[k2] = *(const v8s*)(PsW + lr * 256 + ((((k2 << 2) + lg) ^ lr) << 4));

    // O += P V : B-frag rows = Vt[d][s-chunk]
#pragma unroll
    for (int df = 0; df < 4; ++df) {
      int d = df * 16 + lr;
#pragma unroll
      for (int k2 = 0; k2 < 4; ++k2) {
        v8s vb = *(const v8s*)(VtB + d * 256 + ((((k2 << 2) + lg) ^ lr) << 4));
        O[df] = __builtin_amdgcn_mfma_f32_16x16x32_bf16(pA[k2], vb, O[df], 0, 0, 0);
      }
    }
  }

  // epilogue: Y[b][t][h*64+d] bf16
  int trow = qc * 128 + w * 16 + lg * 4;
  int b = bh >> 4, h = bh & 15;
#pragma unroll
  for (int df = 0; df < 4; ++df) {
    int col = h * 64 + df * 16 + lr;
#pragma unroll
    for (int r = 0; r < 4; ++r) {
      float o = O[df][r] / l[r];
      Yg[((size_t)b * T_SEQ + trow + r) * (NH * HS) + col] = f2bf(o);
    }
  }
}

extern "C" void kernel_launch(void* const* d_in, const int* in_sizes, int n_in,
                              void* d_out, int out_size, void* d_ws, size_t ws_size,
                              hipStream_t stream) {
  (void)in_sizes; (void)n_in; (void)out_size; (void)ws_size;
  const float* x  = (const float*)d_in[0];
  const float* Wq = (const float*)d_in[1];
  const float* Wk = (const float*)d_in[2];
  const float* Wv = (const float*)d_in[3];
  const float* Wo = (const float*)d_in[4];
  const float* bo = (const float*)d_in[5];

  unsigned char* ws = (unsigned char*)d_ws;
  unsigned short* xb  = (unsigned short*)(ws);                      // 8MB
  unsigned short* Wt  = (unsigned short*)(ws + (8u << 20));         // 6MB
  unsigned short* Wot = (unsigned short*)(ws + (14u << 20));        // 2MB
  unsigned short* qkv = (unsigned short*)(ws + (16u << 20));        // 24MB
  unsigned short* Y   = (unsigned short*)(ws + (40u << 20));        // 8MB

  // 1. x -> bf16
  cvt_f32_bf16x4<<<4096, 256, 0, stream>>>(x, xb, (MROWS * CEMB) / 4);

  // 2. weights -> bf16, transposed to [N][K]
  dim3 tb(32, 8);
  transpose_cvt<<<dim3(2, 32, 16), tb, 0, stream>>>(Wq, Wt, 1024, 64);
  transpose_cvt<<<dim3(2, 32, 16), tb, 0, stream>>>(Wk, Wt + (1u << 20), 1024, 64);
  transpose_cvt<<<dim3(2, 32, 16), tb, 0, stream>>>(Wv, Wt + (2u << 20), 1024, 64);
  transpose_cvt<<<dim3(32, 32, 1), tb, 0, stream>>>(Wo, Wot, 1024, 1024);

  // 3. fused QKV projection: [4096][1024] x [3072][1024]^T
  gemm_bt<0><<<dim3(24, 32), 256, 0, stream>>>(xb, Wt, qkv, nullptr, 1024);

  // 4. causal flash attention (V pre-transposed per head: [b][h][64][2048])
  const unsigned short* Qp = qkv;
  const unsigned short* Kp = qkv + (size_t)B_SZ * NH * T_SEQ * HS;
  const unsigned short* Vtp = qkv + (size_t)2 * B_SZ * NH * T_SEQ * HS;
  attn_kernel<<<dim3(512), 512, 0, stream>>>(Qp, Kp, Vtp, Y);

  // 5. output projection + bias -> f32 d_out
  gemm_bt<1><<<dim3(8, 32), 256, 0, stream>>>(Y, Wot, d_out, bo, 1024);
}

// Round 3
// 125.186 us; speedup vs baseline: 1.7537x; 1.3731x over previous
//
#include <hip/hip_runtime.h>

// MHA forward, full-bf16 MFMA pipeline.
// ws layout (bytes): xb[8MB] | Wt[6MB: [3][1024][1024] bf16 N-major] | Wot[2MB]
//                    | qkv[24MB: Q,K:[B][H][T][64], V:[B][H][64][T]] | Y[8MB]

typedef short v8s __attribute__((ext_vector_type(8)));
typedef float v4f __attribute__((ext_vector_type(4)));

#define DEVI __device__ __forceinline__

#define B_SZ 2
#define T_SEQ 2048
#define NH 16
#define HS 64
#define CEMB 1024
#define MROWS (B_SZ * T_SEQ)   // 4096
#define KSZ 1024
// Q scale: 1/sqrt(64) * log2(e)  (attention softmax runs in exp2 domain)
#define SCALE_Q 0.18033688011112042f

DEVI unsigned short f2bf(float f) {
  union { float f; unsigned u; } c; c.f = f;
  unsigned u = c.u;
  unsigned r = (u + 0x7FFFu + ((u >> 16) & 1u)) >> 16;   // RNE
  return (unsigned short)r;
}

DEVI float exp2_fast(float x) {         // v_exp_f32 = 2^x (proven m214 v48)
  float r;
  asm("v_exp_f32 %0, %1" : "=v"(r) : "v"(x));
  return r;
}

DEVI unsigned cvt_pk_bf16(float lo, float hi) {  // packs 2 f32 -> 2 bf16
  unsigned r;
  asm("v_cvt_pk_bf16_f32 %0, %1, %2" : "=v"(r) : "v"(lo), "v"(hi));
  return r;
}

// async global -> LDS, 16B per lane (wave-uniform LDS base + lane*16)
DEVI void gload_lds16(const void* g, void* l) {
  __builtin_amdgcn_global_load_lds(
      (const __attribute__((address_space(1))) void*)g,
      (__attribute__((address_space(3))) void*)l, 16, 0, 0);
}

// ---------------- x -> bf16 ----------------
__global__ void cvt_f32_bf16x4(const float* __restrict__ in,
                               unsigned short* __restrict__ out, int n4) {
  int i = blockIdx.x * blockDim.x + threadIdx.x;
  if (i >= n4) return;
  float4 v = ((const float4*)in)[i];
  ushort4 o;
  o.x = f2bf(v.x); o.y = f2bf(v.y); o.z = f2bf(v.z); o.w = f2bf(v.w);
  ((ushort4*)out)[i] = o;
}

// ------------- transpose f32[R][C] -> bf16[C][R], per z-slice -------------
__global__ void transpose_cvt(const float* __restrict__ in,
                              unsigned short* __restrict__ out, int R, int C) {
  __shared__ float tile[32][33];
  size_t zoff = (size_t)blockIdx.z * R * C;
  in += zoff; out += zoff;
  int c0 = blockIdx.x * 32, r0 = blockIdx.y * 32;
  int tx = threadIdx.x, ty = threadIdx.y;
#pragma unroll
  for (int j = 0; j < 4; ++j) {
    int r = r0 + ty + j * 8;
    tile[ty + j * 8][tx] = in[(size_t)r * C + c0 + tx];
  }
  __syncthreads();
#pragma unroll
  for (int j = 0; j < 4; ++j) {
    int c = c0 + ty + j * 8;
    out[(size_t)c * R + r0 + tx] = f2bf(tile[tx][ty + j * 8]);
  }
}

// ------------- GEMM: C = A[M][1024] x Bt[N][1024]^T, bf16 in, f32 acc -------
// m97 structure: 128x128 tile, BK=32, linear LDS, global_load_lds width=16.
// MODE 0: QKV epilogue -> bf16 scatter; Q scaled by SCALE_Q; V transposed
//         (Q,K: [b][h][t][d], V: [b][h][d][t])
// MODE 1: out-proj epilogue -> f32 [M][1024] + bias
template <int MODE>
__global__ __launch_bounds__(256, 2) void gemm_bt(
    const unsigned short* __restrict__ A, const unsigned short* __restrict__ Bt,
    void* __restrict__ Cout, const float* __restrict__ bias) {
  __shared__ __align__(16) unsigned short As[128 * 32];
  __shared__ __align__(16) unsigned short Bs[128 * 32];

  const int tid = threadIdx.x;
  const int lane = tid & 63, w = tid >> 6;
  const int wm = w >> 1, wn = w & 1;
  const int lr = lane & 15, lg = lane >> 4;
  const int mb = blockIdx.y * 128, nb = blockIdx.x * 128;

  v4f acc[4][4];
  v4f zero = {0.f, 0.f, 0.f, 0.f};
#pragma unroll
  for (int i = 0; i < 4; ++i)
#pragma unroll
    for (int j = 0; j < 4; ++j) acc[i][j] = zero;

  // staging geometry: wave w issue i covers LDS rows w*32+i*16 .. +15
  const int srow = w * 32 + (lane >> 2);          // +16 for issue 1
  const int scol = (lane & 3) * 8;                // element offset, 16B chunks
  const unsigned short* gA = A + (size_t)(mb + srow) * KSZ + scol;
  const unsigned short* gB = Bt + (size_t)(nb + srow) * KSZ + scol;
  unsigned short* lA = As + w * 1024;             // wave-uniform LDS base
  unsigned short* lB = Bs + w * 1024;

  for (int kb = 0; kb < KSZ; kb += 32) {
    __syncthreads();                 // prev iter's ds_reads done
    gload_lds16(gA + kb, lA);
    gload_lds16(gA + kb + 16 * KSZ, lA + 512);
    gload_lds16(gB + kb, lB);
    gload_lds16(gB + kb + 16 * KSZ, lB + 512);
    __syncthreads();                 // compiler drains vmcnt(0) before barrier
    v8s af[4], bfr[4];
#pragma unroll
    for (int i = 0; i < 4; ++i) {
      af[i]  = *(const v8s*)&As[(wm * 64 + i * 16 + lr) * 32 + lg * 8];
      bfr[i] = *(const v8s*)&Bs[(wn * 64 + i * 16 + lr) * 32 + lg * 8];
    }
#pragma unroll
    for (int i = 0; i < 4; ++i)
#pragma unroll
      for (int j = 0; j < 4; ++j)
        acc[i][j] = __builtin_amdgcn_mfma_f32_16x16x32_bf16(af[i], bfr[j], acc[i][j], 0, 0, 0);
  }

#pragma unroll
  for (int i = 0; i < 4; ++i) {
    int mrow0 = mb + wm * 64 + i * 16 + lg * 4;
#pragma unroll
    for (int j = 0; j < 4; ++j) {
      int ncol = nb + wn * 64 + j * 16 + lr;
      if (MODE == 0) {
        int p = ncol >> 10, rem = ncol & 1023, h = rem >> 6, d = rem & 63;
        float sc = (p == 0) ? SCALE_Q : 1.0f;
        unsigned short* out = (unsigned short*)Cout;
#pragma unroll
        for (int r = 0; r < 4; ++r) {
          int mrow = mrow0 + r;
          int b = mrow >> 11, t = mrow & 2047;
          size_t off;
          if (p < 2)
            off = ((size_t)((p * B_SZ + b) * NH + h) * T_SEQ + t) * HS + d;
          else  // V transposed: [b][h][d][t]
            off = (size_t)(2 * B_SZ * NH) * T_SEQ * HS +
                  ((size_t)(b * NH + h) * HS + d) * T_SEQ + t;
          out[off] = f2bf(acc[i][j][r] * sc);
        }
      } else {
        float* out = (float*)Cout;
        float bv = bias[ncol];
#pragma unroll
        for (int r = 0; r < 4; ++r)
          out[(size_t)(mrow0 + r) * CEMB + ncol] = acc[i][j][r] + bv;
      }
    }
  }
}

// ------------- causal flash attention, swapped-operand (S^T / O^T) ---------
// 512 threads = 8 waves; wave w owns q rows qc*128 + w*16 .. +15.
// mfma(K,Q) -> S^T: each lane holds ONE q-row (q = w*16+lr), kv = cf*16+lg*4+r.
// Softmax: in-register reduce + shfl_xor(16,32); m,l are per-lane scalars.
// mfma(Vt,P^T) -> O^T: d = df*16+lg*4+r, q = lr. Same LDS layouts as before.
__global__ __launch_bounds__(512, 4) void attn_kernel(
    const unsigned short* __restrict__ Qg, const unsigned short* __restrict__ Kg,
    const unsigned short* __restrict__ Vtg, unsigned short* __restrict__ Yg) {
  __shared__ __align__(16) unsigned char lds[64 * 1024];
  unsigned char* KsB = lds;             // 16KB [128 s][64 d], chunk-swizzled
  unsigned char* VtB = lds + 16384;     // 16KB [64 d][128 s], chunk-swizzled
  unsigned char* PsB = lds + 32768;     // 32KB, 8 waves x 4KB [16 q][128 kv]

  const int tid = threadIdx.x;
  const int lane = tid & 63, w = tid >> 6;
  const int lr = lane & 15, lg = lane >> 4;
  const int qc = 15 - (blockIdx.x >> 5);   // LPT: longest q-chunk first
  const int bh = blockIdx.x & 31;

  const unsigned short* Qbase = Qg + (size_t)bh * T_SEQ * HS;
  const unsigned short* Kbase = Kg + (size_t)bh * T_SEQ * HS;
  const unsigned short* Vtbase = Vtg + (size_t)bh * T_SEQ * HS;  // [64][2048]

  // staging geometry
  const int ks_row = tid >> 3, ks_cb = tid & 7;
  const int kLds0 = ks_row * 128 + ((ks_cb ^ (ks_row & 7)) << 4);
  const int vs_d = tid >> 4, vs_sc = tid & 15;
  const int vLds0 = vs_d * 256 + ((vs_sc ^ (vs_d & 15)) << 4);
  const unsigned short* Kg0 = Kbase + ks_row * HS + ks_cb * 8;
  const unsigned short* Vg0 = Vtbase + (size_t)vs_d * T_SEQ + vs_sc * 8;

  // Q fragment (B-operand): lane lr -> q row, lg*8 k-offset
  v8s qA[2];
  {
    const unsigned short* qrow = Qbase + (size_t)(qc * 128 + w * 16 + lr) * HS;
    qA[0] = *(const v8s*)(qrow + lg * 8);
    qA[1] = *(const v8s*)(qrow + 32 + lg * 8);
  }

  v4f O[4];
  v4f zero = {0.f, 0.f, 0.f, 0.f};
#pragma unroll
  for (int d = 0; d < 4; ++d) O[d] = zero;
  float mrun = -1e30f, lrun = 0.f;

  unsigned char* PsW = PsB + w * 4096;

  // prologue: tile 0 into regs
  int4 gK0 = *(const int4*)(Kg0);
  int4 gK1 = *(const int4*)(Kg0 + 4096);
  int4 gV0 = *(const int4*)(Vg0);
  int4 gV1 = *(const int4*)(Vg0 + 32 * T_SEQ);

  for (int t = 0; t <= qc; ++t) {
    __syncthreads();  // all reads of previous tile done
    *(int4*)(KsB + kLds0) = gK0;
    *(int4*)(KsB + kLds0 + 8192) = gK1;
    *(int4*)(VtB + vLds0) = gV0;
    *(int4*)(VtB + vLds0 + 8192) = gV1;
    __syncthreads();
    if (t < qc) {  // prefetch next tile (hidden under compute, T14)
      const unsigned short* kp = Kg0 + (t + 1) * (128 * HS);
      gK0 = *(const int4*)kp;
      gK1 = *(const int4*)(kp + 4096);
      const unsigned short* vp = Vg0 + (t + 1) * 128;
      gV0 = *(const int4*)vp;
      gV1 = *(const int4*)(vp + 32 * T_SEQ);
    }

    const int cflim = (t == qc) ? w : 7;          // wave-uniform
    const int k2lim = (t == qc) ? (w >> 1) : 3;

    // S^T = K Q^T : lane q = w*16+lr; S[cf][r] at kv = cf*16+lg*4+r
    v4f S[8];
#pragma unroll
    for (int cf = 0; cf < 8; ++cf) {
      if (cf <= cflim) {
        S[cf] = zero;
#pragma unroll
        for (int ks = 0; ks < 2; ++ks) {
          int srow = cf * 16 + lr;
          v8s kb = *(const v8s*)(KsB + srow * 128 +
                                 ((((ks << 2) + lg) ^ (lr & 7)) << 4));
          S[cf] = __builtin_amdgcn_mfma_f32_16x16x32_bf16(kb, qA[ks], S[cf], 0, 0, 0);
        }
      } else {
        S[cf] = (v4f){-1e30f, -1e30f, -1e30f, -1e30f};
      }
    }

    if (t == qc) {  // causal mask: only cf==w block straddles the diagonal
#pragma unroll
      for (int cf = 0; cf < 8; ++cf)
        if (cf == w) {
#pragma unroll
          for (int r = 0; r < 4; ++r)
            if (lg * 4 + r > lr) S[cf][r] = -1e30f;
        }
    }

    // per-lane online softmax (log2 domain; q fixed = lr)
    float mx = -1e30f;
#pragma unroll
    for (int cf = 0; cf < 8; ++cf)
#pragma unroll
      for (int r = 0; r < 4; ++r) mx = fmaxf(mx, S[cf][r]);
    mx = fmaxf(mx, __shfl_xor(mx, 16));
    mx = fmaxf(mx, __shfl_xor(mx, 32));
    float mn = fmaxf(mrun, mx);
    float alpha = exp2_fast(mrun - mn);
    mrun = mn;
    float sum = 0.f;
#pragma unroll
    for (int cf = 0; cf < 8; ++cf)
#pragma unroll
      for (int r = 0; r < 4; ++r) {
        float p = exp2_fast(S[cf][r] - mn);
        S[cf][r] = p;
        sum += p;
      }
    sum += __shfl_xor(sum, 16);
    sum += __shfl_xor(sum, 32);
    lrun = lrun * alpha + sum;
#pragma unroll
    for (int df = 0; df < 4; ++df)
#pragma unroll
      for (int r = 0; r < 4; ++r) O[df][r] *= alpha;

    // P -> bf16 pairs -> per-wave swizzled LDS (row q=lr, 16 chunks of 16B)
#pragma unroll
    for (int cf = 0; cf < 8; ++cf) {
      unsigned d0 = cvt_pk_bf16(S[cf][0], S[cf][1]);
      unsigned d1 = cvt_pk_bf16(S[cf][2], S[cf][3]);
      int c16 = 2 * cf + (lg >> 1);
      unsigned char* p = PsW + lr * 256 + ((c16 ^ lr) << 4) + ((lg & 1) << 3);
      *(unsigned*)p = d0;
      *(unsigned*)(p + 4) = d1;
    }

    // O^T += V^T P^T
#pragma unroll
    for (int k2 = 0; k2 < 4; ++k2) {
      if (k2 <= k2lim) {
        v8s pa = *(const v8s*)(PsW + lr * 256 + ((((k2 << 2) + lg) ^ lr) << 4));
#pragma unroll
        for (int df = 0; df < 4; ++df) {
          int d = df * 16 + lr;
          v8s vb = *(const v8s*)(VtB + d * 256 + ((((k2 << 2) + lg) ^ lr) << 4));
          O[df] = __builtin_amdgcn_mfma_f32_16x16x32_bf16(vb, pa, O[df], 0, 0, 0);
        }
      }
    }
  }

  // epilogue: lane owns q-row tq; d = df*16+lg*4+r -> 4 consecutive bf16
  float invl = 1.0f / lrun;
  int tq = qc * 128 + w * 16 + lr;
  int b = bh >> 4, h = bh & 15;
  size_t ybase = ((size_t)b * T_SEQ + tq) * (NH * HS) + h * 64;
#pragma unroll
  for (int df = 0; df < 4; ++df) {
    ushort4 o4;
    o4.x = f2bf(O[df][0] * invl);
    o4.y = f2bf(O[df][1] * invl);
    o4.z = f2bf(O[df][2] * invl);
    o4.w = f2bf(O[df][3] * invl);
    *(ushort4*)(Yg + ybase + df * 16 + lg * 4) = o4;
  }
}

extern "C" void kernel_launch(void* const* d_in, const int* in_sizes, int n_in,
                              void* d_out, int out_size, void* d_ws, size_t ws_size,
                              hipStream_t stream) {
  (void)in_sizes; (void)n_in; (void)out_size; (void)ws_size;
  const float* x  = (const float*)d_in[0];
  const float* Wq = (const float*)d_in[1];
  const float* Wk = (const float*)d_in[2];
  const float* Wv = (const float*)d_in[3];
  const float* Wo = (const float*)d_in[4];
  const float* bo = (const float*)d_in[5];

  unsigned char* ws = (unsigned char*)d_ws;
  unsigned short* xb  = (unsigned short*)(ws);                      // 8MB
  unsigned short* Wt  = (unsigned short*)(ws + (8u << 20));         // 6MB
  unsigned short* Wot = (unsigned short*)(ws + (14u << 20));        // 2MB
  unsigned short* qkv = (unsigned short*)(ws + (16u << 20));        // 24MB
  unsigned short* Y   = (unsigned short*)(ws + (40u << 20));        // 8MB

  // 1. x -> bf16
  cvt_f32_bf16x4<<<4096, 256, 0, stream>>>(x, xb, (MROWS * CEMB) / 4);

  // 2. weights -> bf16, transposed to [N][K]
  dim3 tb(32, 8);
  transpose_cvt<<<dim3(2, 32, 16), tb, 0, stream>>>(Wq, Wt, 1024, 64);
  transpose_cvt<<<dim3(2, 32, 16), tb, 0, stream>>>(Wk, Wt + (1u << 20), 1024, 64);
  transpose_cvt<<<dim3(2, 32, 16), tb, 0, stream>>>(Wv, Wt + (2u << 20), 1024, 64);
  transpose_cvt<<<dim3(32, 32, 1), tb, 0, stream>>>(Wo, Wot, 1024, 1024);

  // 3. fused QKV projection: [4096][1024] x [3072][1024]^T
  gemm_bt<0><<<dim3(24, 32), 256, 0, stream>>>(xb, Wt, qkv, nullptr);

  // 4. causal flash attention (V pre-transposed per head: [b][h][64][2048])
  const unsigned short* Qp = qkv;
  const unsigned short* Kp = qkv + (size_t)B_SZ * NH * T_SEQ * HS;
  const unsigned short* Vtp = qkv + (size_t)2 * B_SZ * NH * T_SEQ * HS;
  attn_kernel<<<dim3(512), 512, 0, stream>>>(Qp, Kp, Vtp, Y);

  // 5. output projection + bias -> f32 d_out
  gemm_bt<1><<<dim3(8, 32), 256, 0, stream>>>(Y, Wot, d_out, bo);
}

// Round 4
// 120.647 us; speedup vs baseline: 1.8197x; 1.0376x over previous
//
#include <hip/hip_runtime.h>

// MHA forward, full-bf16 MFMA pipeline.
// ws layout (bytes): xb[8MB] | Wt[6MB: [3][1024][1024] bf16 N-major] | Wot[2MB]
//                    | qkv[24MB: Q,K:[B][H][T][64], V:[B][H][64][T]] | Y[8MB]

typedef short v8s __attribute__((ext_vector_type(8)));
typedef float v4f __attribute__((ext_vector_type(4)));

#define DEVI __device__ __forceinline__

#define B_SZ 2
#define T_SEQ 2048
#define NH 16
#define HS 64
#define CEMB 1024
#define MROWS (B_SZ * T_SEQ)   // 4096
#define KSZ 1024
// Q scale: 1/sqrt(64) * log2(e)  (attention softmax runs in exp2 domain)
#define SCALE_Q 0.18033688011112042f

DEVI unsigned short f2bf(float f) {
  union { float f; unsigned u; } c; c.f = f;
  unsigned u = c.u;
  unsigned r = (u + 0x7FFFu + ((u >> 16) & 1u)) >> 16;   // RNE
  return (unsigned short)r;
}

DEVI float exp2_fast(float x) {         // v_exp_f32 = 2^x
  float r;
  asm("v_exp_f32 %0, %1" : "=v"(r) : "v"(x));
  return r;
}

DEVI unsigned cvt_pk_bf16(float lo, float hi) {  // packs 2 f32 -> 2 bf16
  unsigned r;
  asm("v_cvt_pk_bf16_f32 %0, %1, %2" : "=v"(r) : "v"(lo), "v"(hi));
  return r;
}

// async global -> LDS, 16B per lane (wave-uniform LDS base + lane*16)
DEVI void gload_lds16(const void* g, void* l) {
  __builtin_amdgcn_global_load_lds(
      (const __attribute__((address_space(1))) void*)g,
      (__attribute__((address_space(3))) void*)l, 16, 0, 0);
}

// ---------------- x -> bf16 ----------------
__global__ void cvt_f32_bf16x4(const float* __restrict__ in,
                               unsigned short* __restrict__ out, int n4) {
  int i = blockIdx.x * blockDim.x + threadIdx.x;
  if (i >= n4) return;
  float4 v = ((const float4*)in)[i];
  ushort4 o;
  o.x = f2bf(v.x); o.y = f2bf(v.y); o.z = f2bf(v.z); o.w = f2bf(v.w);
  ((ushort4*)out)[i] = o;
}

// ------------- transpose f32[R][C] -> bf16[C][R], per z-slice -------------
__global__ void transpose_cvt(const float* __restrict__ in,
                              unsigned short* __restrict__ out, int R, int C) {
  __shared__ float tile[32][33];
  size_t zoff = (size_t)blockIdx.z * R * C;
  in += zoff; out += zoff;
  int c0 = blockIdx.x * 32, r0 = blockIdx.y * 32;
  int tx = threadIdx.x, ty = threadIdx.y;
#pragma unroll
  for (int j = 0; j < 4; ++j) {
    int r = r0 + ty + j * 8;
    tile[ty + j * 8][tx] = in[(size_t)r * C + c0 + tx];
  }
  __syncthreads();
#pragma unroll
  for (int j = 0; j < 4; ++j) {
    int c = c0 + ty + j * 8;
    out[(size_t)c * R + r0 + tx] = f2bf(tile[tx][ty + j * 8]);
  }
}

// ------------- GEMM: C = A[M][1024] x Bt[N][1024]^T, bf16 in, f32 acc -------
// 2-phase double-buffered (T3-min): STAGE(t+1) issued BEFORE compute(t);
// single barrier per K-step (its vmcnt(0) drain lands after ~400cy of MFMA).
// LDS linear for global_load_lds; bank-conflict fix via pre-swizzled global
// source chunk (c16 ^= row&3) + same XOR on fragment reads (rule #21).
// MODE 0: QKV epilogue -> bf16 scatter; Q scaled by SCALE_Q; V transposed
//         (Q,K: [b][h][t][d], V: [b][h][d][t])
// MODE 1: out-proj epilogue -> f32 [M][1024] + bias
template <int MODE>
__global__ __launch_bounds__(256, 4) void gemm_bt(
    const unsigned short* __restrict__ A, const unsigned short* __restrict__ Bt,
    void* __restrict__ Cout, const float* __restrict__ bias) {
  __shared__ __align__(16) unsigned short As[2][128 * 32];   // 8KB x2
  __shared__ __align__(16) unsigned short Bs[2][128 * 32];   // 8KB x2

  const int tid = threadIdx.x;
  const int lane = tid & 63, w = tid >> 6;
  const int wm = w >> 1, wn = w & 1;
  const int lr = lane & 15, lg = lane >> 4;
  const int mb = blockIdx.y * 128, nb = blockIdx.x * 128;

  v4f acc[4][4];
  v4f zero = {0.f, 0.f, 0.f, 0.f};
#pragma unroll
  for (int i = 0; i < 4; ++i)
#pragma unroll
    for (int j = 0; j < 4; ++j) acc[i][j] = zero;

  // staging: wave w covers tile rows w*32..w*32+31 (2 issues/matrix, 16 rows ea)
  // lane -> row = base + (lane>>2); fetches global chunk (lane&3)^((lane>>2)&3)
  const int srow = lane >> 2;
  const int sgcol = ((lane & 3) ^ (srow & 3)) * 8;
  const unsigned short* gA = A + (size_t)(mb + w * 32 + srow) * KSZ + sgcol;
  const unsigned short* gB = Bt + (size_t)(nb + w * 32 + srow) * KSZ + sgcol;
  unsigned short* lA = &As[0][0] + w * 1024;   // wave-uniform; +4096 for buf 1
  unsigned short* lB = &Bs[0][0] + w * 1024;

#define STAGE_G(cur, kb)                                    \
  do {                                                      \
    gload_lds16(gA + (kb), lA + (cur) * 4096);              \
    gload_lds16(gA + (kb) + 16 * KSZ, lA + (cur) * 4096 + 512); \
    gload_lds16(gB + (kb), lB + (cur) * 4096);              \
    gload_lds16(gB + (kb) + 16 * KSZ, lB + (cur) * 4096 + 512); \
  } while (0)

  STAGE_G(0, 0);
  __syncthreads();               // tile 0 ready (vmcnt(0) drained here)
  int cur = 0;

  for (int kb = 0; kb < KSZ; kb += 32) {
    if (kb + 32 < KSZ) STAGE_G(cur ^ 1, kb + 32);   // issue next tile's DMA
    v8s af[4], bfr[4];
#pragma unroll
    for (int i = 0; i < 4; ++i) {
      int ra = wm * 64 + i * 16 + lr, rb = wn * 64 + i * 16 + lr;
      af[i]  = *(const v8s*)&As[cur][ra * 32 + ((lg ^ (lr & 3)) << 3)];
      bfr[i] = *(const v8s*)&Bs[cur][rb * 32 + ((lg ^ (lr & 3)) << 3)];
    }
#pragma unroll
    for (int i = 0; i < 4; ++i)
#pragma unroll
      for (int j = 0; j < 4; ++j)
        acc[i][j] = __builtin_amdgcn_mfma_f32_16x16x32_bf16(af[i], bfr[j], acc[i][j], 0, 0, 0);
    __syncthreads();             // drains next tile's DMA + this tile's reads
    cur ^= 1;
  }
#undef STAGE_G

#pragma unroll
  for (int i = 0; i < 4; ++i) {
    int mrow0 = mb + wm * 64 + i * 16 + lg * 4;
#pragma unroll
    for (int j = 0; j < 4; ++j) {
      int ncol = nb + wn * 64 + j * 16 + lr;
      if (MODE == 0) {
        int p = ncol >> 10, rem = ncol & 1023, h = rem >> 6, d = rem & 63;
        float sc = (p == 0) ? SCALE_Q : 1.0f;
        unsigned short* out = (unsigned short*)Cout;
#pragma unroll
        for (int r = 0; r < 4; ++r) {
          int mrow = mrow0 + r;
          int b = mrow >> 11, t = mrow & 2047;
          size_t off;
          if (p < 2)
            off = ((size_t)((p * B_SZ + b) * NH + h) * T_SEQ + t) * HS + d;
          else  // V transposed: [b][h][d][t]
            off = (size_t)(2 * B_SZ * NH) * T_SEQ * HS +
                  ((size_t)(b * NH + h) * HS + d) * T_SEQ + t;
          out[off] = f2bf(acc[i][j][r] * sc);
        }
      } else {
        float* out = (float*)Cout;
        float bv = bias[ncol];
#pragma unroll
        for (int r = 0; r < 4; ++r)
          out[(size_t)(mrow0 + r) * CEMB + ncol] = acc[i][j][r] + bv;
      }
    }
  }
}

// ------------- causal flash attention, swapped-operand (S^T / O^T) ---------
// 512 threads = 8 waves; wave w owns q rows qc*128 + w*16 .. +15.
// mfma(K,Q) -> S^T: each lane holds ONE q-row (q = w*16+lr), kv = cf*16+lg*4+r.
// Softmax: in-register reduce + shfl_xor(16,32); m,l are per-lane scalars.
// mfma(Vt,P^T) -> O^T: d = df*16+lg*4+r, q = lr.
__global__ __launch_bounds__(512, 4) void attn_kernel(
    const unsigned short* __restrict__ Qg, const unsigned short* __restrict__ Kg,
    const unsigned short* __restrict__ Vtg, unsigned short* __restrict__ Yg) {
  __shared__ __align__(16) unsigned char lds[64 * 1024];
  unsigned char* KsB = lds;             // 16KB [128 s][64 d], chunk-swizzled
  unsigned char* VtB = lds + 16384;     // 16KB [64 d][128 s], chunk-swizzled
  unsigned char* PsB = lds + 32768;     // 32KB, 8 waves x 4KB [16 q][128 kv]

  const int tid = threadIdx.x;
  const int lane = tid & 63, w = tid >> 6;
  const int lr = lane & 15, lg = lane >> 4;
  const int qc = 15 - (blockIdx.x >> 5);   // LPT: longest q-chunk first
  const int bh = blockIdx.x & 31;

  const unsigned short* Qbase = Qg + (size_t)bh * T_SEQ * HS;
  const unsigned short* Kbase = Kg + (size_t)bh * T_SEQ * HS;
  const unsigned short* Vtbase = Vtg + (size_t)bh * T_SEQ * HS;  // [64][2048]

  // staging geometry
  const int ks_row = tid >> 3, ks_cb = tid & 7;
  const int kLds0 = ks_row * 128 + ((ks_cb ^ (ks_row & 7)) << 4);
  const int vs_d = tid >> 4, vs_sc = tid & 15;
  const int vLds0 = vs_d * 256 + ((vs_sc ^ (vs_d & 15)) << 4);
  const unsigned short* Kg0 = Kbase + ks_row * HS + ks_cb * 8;
  const unsigned short* Vg0 = Vtbase + (size_t)vs_d * T_SEQ + vs_sc * 8;

  // Q fragment (B-operand): lane lr -> q row, lg*8 k-offset
  v8s qA[2];
  {
    const unsigned short* qrow = Qbase + (size_t)(qc * 128 + w * 16 + lr) * HS;
    qA[0] = *(const v8s*)(qrow + lg * 8);
    qA[1] = *(const v8s*)(qrow + 32 + lg * 8);
  }

  v4f O[4];
  v4f zero = {0.f, 0.f, 0.f, 0.f};
#pragma unroll
  for (int d = 0; d < 4; ++d) O[d] = zero;
  float mrun = -1e30f, lrun = 0.f;

  unsigned char* PsW = PsB + w * 4096;

  // prologue: tile 0 into regs
  int4 gK0 = *(const int4*)(Kg0);
  int4 gK1 = *(const int4*)(Kg0 + 4096);
  int4 gV0 = *(const int4*)(Vg0);
  int4 gV1 = *(const int4*)(Vg0 + 32 * T_SEQ);

  for (int t = 0; t <= qc; ++t) {
    __syncthreads();  // all reads of previous tile done
    *(int4*)(KsB + kLds0) = gK0;
    *(int4*)(KsB + kLds0 + 8192) = gK1;
    *(int4*)(VtB + vLds0) = gV0;
    *(int4*)(VtB + vLds0 + 8192) = gV1;
    __syncthreads();
    if (t < qc) {  // prefetch next tile (hidden under compute, T14)
      const unsigned short* kp = Kg0 + (t + 1) * (128 * HS);
      gK0 = *(const int4*)kp;
      gK1 = *(const int4*)(kp + 4096);
      const unsigned short* vp = Vg0 + (t + 1) * 128;
      gV0 = *(const int4*)vp;
      gV1 = *(const int4*)(vp + 32 * T_SEQ);
    }

    const int cflim = (t == qc) ? w : 7;          // wave-uniform
    const int k2lim = (t == qc) ? (w >> 1) : 3;

    // S^T = K Q^T : lane q = w*16+lr; S[cf][r] at kv = cf*16+lg*4+r
    v4f S[8];
#pragma unroll
    for (int cf = 0; cf < 8; ++cf) {
      if (cf <= cflim) {
        S[cf] = zero;
#pragma unroll
        for (int ks = 0; ks < 2; ++ks) {
          int srow = cf * 16 + lr;
          v8s kb = *(const v8s*)(KsB + srow * 128 +
                                 ((((ks << 2) + lg) ^ (lr & 7)) << 4));
          S[cf] = __builtin_amdgcn_mfma_f32_16x16x32_bf16(kb, qA[ks], S[cf], 0, 0, 0);
        }
      } else {
        S[cf] = (v4f){-1e30f, -1e30f, -1e30f, -1e30f};
      }
    }

    if (t == qc) {  // causal mask: only cf==w block straddles the diagonal
#pragma unroll
      for (int cf = 0; cf < 8; ++cf)
        if (cf == w) {
#pragma unroll
          for (int r = 0; r < 4; ++r)
            if (lg * 4 + r > lr) S[cf][r] = -1e30f;
        }
    }

    // per-lane online softmax (exp2 domain; q fixed = lr)
    float mx = -1e30f;
#pragma unroll
    for (int cf = 0; cf < 8; ++cf)
#pragma unroll
      for (int r = 0; r < 4; ++r) mx = fmaxf(mx, S[cf][r]);
    mx = fmaxf(mx, __shfl_xor(mx, 16));
    mx = fmaxf(mx, __shfl_xor(mx, 32));
    float mn = fmaxf(mrun, mx);
    float alpha = exp2_fast(mrun - mn);
    mrun = mn;
    float sum = 0.f;
#pragma unroll
    for (int cf = 0; cf < 8; ++cf)
#pragma unroll
      for (int r = 0; r < 4; ++r) {
        float p = exp2_fast(S[cf][r] - mn);
        S[cf][r] = p;
        sum += p;
      }
    sum += __shfl_xor(sum, 16);
    sum += __shfl_xor(sum, 32);
    lrun = lrun * alpha + sum;
#pragma unroll
    for (int df = 0; df < 4; ++df)
#pragma unroll
      for (int r = 0; r < 4; ++r) O[df][r] *= alpha;

    // P -> bf16 pairs -> per-wave swizzled LDS (row q=lr, 16 chunks of 16B)
#pragma unroll
    for (int cf = 0; cf < 8; ++cf) {
      unsigned d0 = cvt_pk_bf16(S[cf][0], S[cf][1]);
      unsigned d1 = cvt_pk_bf16(S[cf][2], S[cf][3]);
      int c16 = 2 * cf + (lg >> 1);
      unsigned char* p = PsW + lr * 256 + ((c16 ^ lr) << 4) + ((lg & 1) << 3);
      *(unsigned*)p = d0;
      *(unsigned*)(p + 4) = d1;
    }

    // O^T += V^T P^T
#pragma unroll
    for (int k2 = 0; k2 < 4; ++k2) {
      if (k2 <= k2lim) {
        v8s pa = *(const v8s*)(PsW + lr * 256 + ((((k2 << 2) + lg) ^ lr) << 4));
#pragma unroll
        for (int df = 0; df < 4; ++df) {
          int d = df * 16 + lr;
          v8s vb = *(const v8s*)(VtB + d * 256 + ((((k2 << 2) + lg) ^ lr) << 4));
          O[df] = __builtin_amdgcn_mfma_f32_16x16x32_bf16(vb, pa, O[df], 0, 0, 0);
        }
      }
    }
  }

  // epilogue: lane owns q-row tq; d = df*16+lg*4+r -> 4 consecutive bf16
  float invl = 1.0f / lrun;
  int tq = qc * 128 + w * 16 + lr;
  int b = bh >> 4, h = bh & 15;
  size_t ybase = ((size_t)b * T_SEQ + tq) * (NH * HS) + h * 64;
#pragma unroll
  for (int df = 0; df < 4; ++df) {
    ushort4 o4;
    o4.x = f2bf(O[df][0] * invl);
    o4.y = f2bf(O[df][1] * invl);
    o4.z = f2bf(O[df][2] * invl);
    o4.w = f2bf(O[df][3] * invl);
    *(ushort4*)(Yg + ybase + df * 16 + lg * 4) = o4;
  }
}

extern "C" void kernel_launch(void* const* d_in, const int* in_sizes, int n_in,
                              void* d_out, int out_size, void* d_ws, size_t ws_size,
                              hipStream_t stream) {
  (void)in_sizes; (void)n_in; (void)out_size; (void)ws_size;
  const float* x  = (const float*)d_in[0];
  const float* Wq = (const float*)d_in[1];
  const float* Wk = (const float*)d_in[2];
  const float* Wv = (const float*)d_in[3];
  const float* Wo = (const float*)d_in[4];
  const float* bo = (const float*)d_in[5];

  unsigned char* ws = (unsigned char*)d_ws;
  unsigned short* xb  = (unsigned short*)(ws);                      // 8MB
  unsigned short* Wt  = (unsigned short*)(ws + (8u << 20));         // 6MB
  unsigned short* Wot = (unsigned short*)(ws + (14u << 20));        // 2MB
  unsigned short* qkv = (unsigned short*)(ws + (16u << 20));        // 24MB
  unsigned short* Y   = (unsigned short*)(ws + (40u << 20));        // 8MB

  // 1. x -> bf16
  cvt_f32_bf16x4<<<4096, 256, 0, stream>>>(x, xb, (MROWS * CEMB) / 4);

  // 2. weights -> bf16, transposed to [N][K]
  dim3 tb(32, 8);
  transpose_cvt<<<dim3(2, 32, 16), tb, 0, stream>>>(Wq, Wt, 1024, 64);
  transpose_cvt<<<dim3(2, 32, 16), tb, 0, stream>>>(Wk, Wt + (1u << 20), 1024, 64);
  transpose_cvt<<<dim3(2, 32, 16), tb, 0, stream>>>(Wv, Wt + (2u << 20), 1024, 64);
  transpose_cvt<<<dim3(32, 32, 1), tb, 0, stream>>>(Wo, Wot, 1024, 1024);

  // 3. fused QKV projection: [4096][1024] x [3072][1024]^T
  gemm_bt<0><<<dim3(24, 32), 256, 0, stream>>>(xb, Wt, qkv, nullptr);

  // 4. causal flash attention (V pre-transposed per head: [b][h][64][2048])
  const unsigned short* Qp = qkv;
  const unsigned short* Kp = qkv + (size_t)B_SZ * NH * T_SEQ * HS;
  const unsigned short* Vtp = qkv + (size_t)2 * B_SZ * NH * T_SEQ * HS;
  attn_kernel<<<dim3(512), 512, 0, stream>>>(Qp, Kp, Vtp, Y);

  // 5. output projection + bias -> f32 d_out
  gemm_bt<1><<<dim3(8, 32), 256, 0, stream>>>(Y, Wot, d_out, bo);
}